// Round 2
// baseline (4242.507 us; speedup 1.0000x reference)
//
#include <hip/hip_runtime.h>

typedef unsigned int uint;
typedef unsigned short ushort;

// B=16 L=512 H=12 d=64 D=768 N3=2304 C=20 M=8192

__device__ __forceinline__ float b2f(ushort u){ return __uint_as_float(((uint)u)<<16); }
__device__ __forceinline__ ushort f2b(float f){
  uint u = __float_as_uint(f);
  uint r = u + 0x7fffu + ((u>>16)&1u);
  return (ushort)(r>>16);
}
__device__ __forceinline__ float leaky(float x){ return x >= 0.f ? x : 0.01f*x; }
__device__ __forceinline__ float ldf(const void* p, int idx, int isb){
  return isb ? b2f(((const ushort*)p)[idx]) : ((const float*)p)[idx];
}

// ---------- K-1: detect whether float tensors arrived as bf16 (1) or f32 (0) ----------
__global__ void k_detect(const ushort* __restrict__ wvbits, int* __restrict__ flag){
  if (blockIdx.x==0 && threadIdx.x==0){
    int sane = 0;
    for (int i=0;i<128;i++){
      uint e = (wvbits[i]>>7)&0xffu;
      if (e==0u || (e>=90u && e<=150u)) sane++;
    }
    *flag = (sane >= 115) ? 1 : 0;   // bf16: ~128/128 sane; f32: ~79/128
  }
}

// ---------- K0: X[m,k] = leaky(emb[ids[m],k])  (f32 out) ----------
__global__ __launch_bounds__(256) void k_build_x(const int* __restrict__ ids,
    const void* __restrict__ emb, float* __restrict__ X, const int* __restrict__ flag){
  int isb = *flag;
  int t = blockIdx.x*256 + threadIdx.x;      // 786432 threads, 8 elems each
  int m = t / 96;
  int kk = (t % 96) * 8;
  float o[8];
  if (isb){
    const ushort* src = (const ushort*)emb + (size_t)ids[m]*768 + kk;
    uint4 v = *(const uint4*)src;
    o[0]=__uint_as_float((v.x&0xffffu)<<16); o[1]=__uint_as_float(v.x&0xffff0000u);
    o[2]=__uint_as_float((v.y&0xffffu)<<16); o[3]=__uint_as_float(v.y&0xffff0000u);
    o[4]=__uint_as_float((v.z&0xffffu)<<16); o[5]=__uint_as_float(v.z&0xffff0000u);
    o[6]=__uint_as_float((v.w&0xffffu)<<16); o[7]=__uint_as_float(v.w&0xffff0000u);
  } else {
    const float* src = (const float*)emb + (size_t)ids[m]*768 + kk;
    float4 v0 = ((const float4*)src)[0];
    float4 v1 = ((const float4*)src)[1];
    o[0]=v0.x; o[1]=v0.y; o[2]=v0.z; o[3]=v0.w;
    o[4]=v1.x; o[5]=v1.y; o[6]=v1.z; o[7]=v1.w;
  }
  float* dst = X + (size_t)m*768 + kk;
  #pragma unroll
  for (int i=0;i<8;i++) dst[i] = leaky(o[i]);
}

// ---------- K1: QKV GEMM: y = leaky(A @ W^T + b), scatter to Q/K/V [B,H,L,d] ----------
__global__ __launch_bounds__(256) void k_gemm_qkv(const float* __restrict__ Aws,
    const void* __restrict__ Aext, const void* __restrict__ W,
    const void* __restrict__ bias, int K, const int* __restrict__ flag,
    float* __restrict__ Qb, float* __restrict__ Kb, ushort* __restrict__ Vb){
  __shared__ __align__(16) float As[16][68];
  __shared__ __align__(16) float Bs[16][68];
  int isb = *flag;
  int tid = threadIdx.x;
  int tx = tid & 15, ty = tid >> 4;
  int m0 = blockIdx.x * 64, n0 = blockIdx.y * 64;
  int ml = tid >> 2;            // 0..63
  int kq = (tid & 3) << 2;      // 0,4,8,12
  float acc[4][4] = {};
  int steps = (K + 15) >> 4;
  for (int s0 = 0; s0 < steps; s0++){
    int k = s0*16 + kq;
    float a0=0.f,a1=0.f,a2=0.f,a3=0.f, b0=0.f,b1=0.f,b2=0.f,b3=0.f;
    if (k < K){
      if (Aws){
        float4 va = *(const float4*)(Aws + (size_t)(m0+ml)*K + k);
        a0=va.x; a1=va.y; a2=va.z; a3=va.w;
      } else if (isb){
        uint2 va = *(const uint2*)((const ushort*)Aext + (size_t)(m0+ml)*K + k);
        a0=__uint_as_float((va.x&0xffffu)<<16); a1=__uint_as_float(va.x&0xffff0000u);
        a2=__uint_as_float((va.y&0xffffu)<<16); a3=__uint_as_float(va.y&0xffff0000u);
      } else {
        float4 va = *(const float4*)((const float*)Aext + (size_t)(m0+ml)*K + k);
        a0=va.x; a1=va.y; a2=va.z; a3=va.w;
      }
      if (isb){
        uint2 vb = *(const uint2*)((const ushort*)W + (size_t)(n0+ml)*K + k);
        b0=__uint_as_float((vb.x&0xffffu)<<16); b1=__uint_as_float(vb.x&0xffff0000u);
        b2=__uint_as_float((vb.y&0xffffu)<<16); b3=__uint_as_float(vb.y&0xffff0000u);
      } else {
        float4 vb = *(const float4*)((const float*)W + (size_t)(n0+ml)*K + k);
        b0=vb.x; b1=vb.y; b2=vb.z; b3=vb.w;
      }
    }
    As[kq+0][ml]=a0; As[kq+1][ml]=a1; As[kq+2][ml]=a2; As[kq+3][ml]=a3;
    Bs[kq+0][ml]=b0; Bs[kq+1][ml]=b1; Bs[kq+2][ml]=b2; Bs[kq+3][ml]=b3;
    __syncthreads();
    #pragma unroll
    for (int kt=0; kt<16; kt++){
      float4 av = *(const float4*)&As[kt][ty*4];
      float4 bv = *(const float4*)&Bs[kt][tx*4];
      acc[0][0] += av.x*bv.x; acc[0][1] += av.x*bv.y; acc[0][2] += av.x*bv.z; acc[0][3] += av.x*bv.w;
      acc[1][0] += av.y*bv.x; acc[1][1] += av.y*bv.y; acc[1][2] += av.y*bv.z; acc[1][3] += av.y*bv.w;
      acc[2][0] += av.z*bv.x; acc[2][1] += av.z*bv.y; acc[2][2] += av.z*bv.z; acc[2][3] += av.z*bv.w;
      acc[3][0] += av.w*bv.x; acc[3][1] += av.w*bv.y; acc[3][2] += av.w*bv.z; acc[3][3] += av.w*bv.w;
    }
    __syncthreads();
  }
  // epilogue: n0 spans exactly one (s,h): 64 cols
  int s = n0 / 768;
  int h = (n0 % 768) >> 6;
  #pragma unroll
  for (int i=0;i<4;i++){
    int m = m0 + ty*4 + i;
    int bq = m >> 9, l = m & 511;
    size_t rowbase = ((size_t)(bq*12 + h)*512 + l)*64;
    #pragma unroll
    for (int j=0;j<4;j++){
      int dd = tx*4 + j;
      float y = acc[i][j] + ldf(bias, n0 + dd, isb);
      y = leaky(y);
      if (s == 0)      Qb[rowbase + dd] = y;
      else if (s == 1) Kb[rowbase + dd] = y;
      else             Vb[rowbase + dd] = f2b(y);
    }
  }
}

// ---------- K2: row-normalize Q,K (over d=64) in place; also zero colsum ----------
__global__ __launch_bounds__(256) void k_norm(float* __restrict__ Qb, float* __restrict__ Kb,
    float* __restrict__ colsum){
  int tid = threadIdx.x;
  int wv = tid >> 6, lane = tid & 63;
  int row = blockIdx.x*4 + wv;              // [B*H*L)
  size_t base = (size_t)row*64 + lane;
  float q = Qb[base];
  float ssq = q*q;
  #pragma unroll
  for (int off=1; off<64; off<<=1) ssq += __shfl_xor(ssq, off, 64);
  Qb[base] = q / fmaxf(sqrtf(ssq), 1e-8f);
  float k = Kb[base];
  float ssk = k*k;
  #pragma unroll
  for (int off=1; off<64; off<<=1) ssk += __shfl_xor(ssk, off, 64);
  Kb[base] = k / fmaxf(sqrtf(ssk), 1e-8f);
  if (blockIdx.x < 32) colsum[blockIdx.x*256 + tid] = 0.f;
}

// ---------- K3: attention: scores -> head-LN -> softmax -> colsum -> P@V ----------
__global__ __launch_bounds__(256) void k_attn(const float* __restrict__ Qb,
    const float* __restrict__ Kb, const ushort* __restrict__ Vb,
    const void* __restrict__ gamma, const void* __restrict__ beta,
    const int* __restrict__ flag,
    float* __restrict__ O, float* __restrict__ colsum){
  __shared__ float S[12][512];
  __shared__ float Krow[12][64];
  __shared__ float g[12], be[12];
  int tid = threadIdx.x;
  int b = blockIdx.x >> 9, i = blockIdx.x & 511;
  int wv = tid >> 6, lane = tid & 63;
  #pragma unroll
  for (int r=0;r<3;r++){
    int idx = tid + r*256;
    int h = idx >> 6, dd = idx & 63;
    Krow[h][dd] = Kb[((size_t)(b*12+h)*512 + i)*64 + dd];
  }
  if (tid < 12){
    int isb = *flag;
    g[tid] = ldf(gamma, tid, isb); be[tid] = ldf(beta, tid, isb);
  }
  __syncthreads();
  // scores: wave wv handles heads 3wv..3wv+2; K-row i cached in registers
  #pragma unroll
  for (int hh=0; hh<3; hh++){
    int h = wv*3 + hh;
    float kf[64];
    #pragma unroll
    for (int q=0;q<16;q++){
      float4 t = *(const float4*)&Krow[h][q*4];
      kf[q*4+0]=t.x; kf[q*4+1]=t.y; kf[q*4+2]=t.z; kf[q*4+3]=t.w;
    }
    const float* qbase = Qb + ((size_t)(b*12+h)*512)*64;
    for (int jb=0; jb<8; jb++){
      int j = jb*64 + lane;
      const float4* qr = (const float4*)(qbase + (size_t)j*64);
      float acc = 0.f;
      #pragma unroll
      for (int q=0;q<16;q++){
        float4 t = qr[q];
        acc += t.x*kf[q*4+0] + t.y*kf[q*4+1] + t.z*kf[q*4+2] + t.w*kf[q*4+3];
      }
      S[h][j] = acc;
    }
  }
  __syncthreads();
  // LayerNorm over heads at each column j (biased var, eps=1e-5)
  #pragma unroll
  for (int r=0;r<2;r++){
    int j = tid + r*256;
    float sum=0.f, sq=0.f;
    #pragma unroll
    for (int h=0;h<12;h++){ float x=S[h][j]; sum+=x; sq+=x*x; }
    float mu = sum*(1.f/12.f);
    float var = fmaxf(sq*(1.f/12.f) - mu*mu, 0.f);
    float rs = rsqrtf(var + 1e-5f);
    #pragma unroll
    for (int h=0;h<12;h++) S[h][j] = (S[h][j]-mu)*rs*g[h] + be[h];
  }
  __syncthreads();
  // softmax over j for each head row
  #pragma unroll
  for (int hh=0; hh<3; hh++){
    int h = wv*3 + hh;
    float v[8]; float mx = -3.4e38f;
    #pragma unroll
    for (int r=0;r<8;r++){ v[r] = S[h][r*64 + lane]; mx = fmaxf(mx, v[r]); }
    #pragma unroll
    for (int off=1; off<64; off<<=1) mx = fmaxf(mx, __shfl_xor(mx, off, 64));
    float s = 0.f;
    #pragma unroll
    for (int r=0;r<8;r++){ v[r] = __expf(v[r]-mx); s += v[r]; }
    #pragma unroll
    for (int off=1; off<64; off<<=1) s += __shfl_xor(s, off, 64);
    float inv = 1.f/s;
    #pragma unroll
    for (int r=0;r<8;r++) S[h][r*64+lane] = v[r]*inv;
  }
  __syncthreads();
  // colsum[b,j] += mean_h P[h][j]   (sum over rows i via atomics)
  #pragma unroll
  for (int r=0;r<2;r++){
    int j = tid + r*256;
    float s = 0.f;
    #pragma unroll
    for (int h=0;h<12;h++) s += S[h][j];
    atomicAdd(&colsum[b*512 + j], s*(1.f/12.f));
  }
  // O[b,i,h*64+dd] = sum_j P[h][j] * V[b,h,j,dd]
  #pragma unroll
  for (int rep=0; rep<3; rep++){
    int idx = rep*256 + tid;
    int h = idx >> 6, dd = idx & 63;
    const ushort* vp = Vb + ((size_t)(b*12+h)*512)*64 + dd;
    float acc = 0.f;
    #pragma unroll 8
    for (int j=0;j<512;j++){
      acc += S[h][j] * b2f(vp[(size_t)j*64]);
    }
    O[(size_t)(b*512+i)*768 + idx] = acc;
  }
}

// ---------- K4: probs[m,:] = softmax(O[m,:] @ Wout^T + bout) ----------
__global__ __launch_bounds__(256) void k_probs(const float* __restrict__ O,
    const void* __restrict__ Wout, const void* __restrict__ bout,
    const int* __restrict__ flag, float* __restrict__ probs){
  int isb = *flag;
  int tid = threadIdx.x, wv = tid>>6, lane = tid&63;
  int m = blockIdx.x*4 + wv;
  const float* orow = O + (size_t)m*768;
  float acc[20];
  #pragma unroll
  for (int c=0;c<20;c++) acc[c]=0.f;
  for (int kk=0; kk<12; kk++){
    float o = orow[kk*64 + lane];
    #pragma unroll
    for (int c=0;c<20;c++)
      acc[c] += o * ldf(Wout, c*768 + kk*64 + lane, isb);
  }
  #pragma unroll
  for (int c=0;c<20;c++){
    #pragma unroll
    for (int off=1; off<64; off<<=1) acc[c] += __shfl_xor(acc[c], off, 64);
  }
  float mx = -3.4e38f;
  #pragma unroll
  for (int c=0;c<20;c++){ acc[c] += ldf(bout, c, isb); mx = fmaxf(mx, acc[c]); }
  float s=0.f;
  #pragma unroll
  for (int c=0;c<20;c++){ acc[c] = __expf(acc[c]-mx); s += acc[c]; }
  float inv = 1.f/s;
  if (lane == 0){
    float* pr = probs + (size_t)m*20;
    #pragma unroll
    for (int c=0;c<20;c++) pr[c] = acc[c]*inv;
  }
}

// ---------- K5: weights = softmax(mask*colsum); out[b,:] = sum_l w[l]*probs[b,l,:] ----------
__global__ __launch_bounds__(512) void k_final(const int* __restrict__ ids,
    const float* __restrict__ colsum, const float* __restrict__ probs,
    const int* __restrict__ flag,
    float* __restrict__ accb, void* __restrict__ outp, int br){
  __shared__ float red[8];
  __shared__ float bcast;
  __shared__ float pacc[8][20];
  int b = blockIdx.x, tid = threadIdx.x;
  int wv = tid>>6, lane = tid&63;
  float w = (ids[b*512+tid] != 0) ? colsum[b*512+tid] : 0.f;
  float mx = w;
  #pragma unroll
  for (int off=1; off<64; off<<=1) mx = fmaxf(mx, __shfl_xor(mx, off, 64));
  if (lane==0) red[wv] = mx;
  __syncthreads();
  if (tid==0){ float m2 = red[0]; for (int k2=1;k2<8;k2++) m2 = fmaxf(m2, red[k2]); bcast = m2; }
  __syncthreads();
  float M = bcast;
  float e = __expf(w - M);
  float s = e;
  #pragma unroll
  for (int off=1; off<64; off<<=1) s += __shfl_xor(s, off, 64);
  if (lane==0) red[wv] = s;
  __syncthreads();
  if (tid==0){ float s2=0.f; for (int k2=0;k2<8;k2++) s2 += red[k2]; bcast = s2; }
  __syncthreads();
  float wn = e / bcast;
  float p[20];
  const float* pr = probs + ((size_t)b*512 + tid)*20;
  #pragma unroll
  for (int c=0;c<20;c++) p[c] = wn * pr[c];
  #pragma unroll
  for (int c=0;c<20;c++){
    #pragma unroll
    for (int off=1; off<64; off<<=1) p[c] += __shfl_xor(p[c], off, 64);
  }
  if (lane==0){
    #pragma unroll
    for (int c=0;c<20;c++) pacc[wv][c] = p[c];
  }
  __syncthreads();
  if (tid < 20){
    float s2 = 0.f;
    #pragma unroll
    for (int k2=0;k2<8;k2++) s2 += pacc[k2][tid];
    if (br == 0) accb[b*20 + tid] = s2;
    else {
      float v = (accb[b*20 + tid] + s2) * 0.5f;
      if (*flag) ((ushort*)outp)[b*20 + tid] = f2b(v);
      else       ((float*)outp)[b*20 + tid] = v;
    }
  }
}

extern "C" void kernel_launch(void* const* d_in, const int* in_sizes, int n_in,
                              void* d_out, int out_size, void* d_ws, size_t ws_size,
                              hipStream_t stream){
  (void)in_sizes; (void)n_in; (void)out_size; (void)ws_size;
  const int*  ids = (const int*)d_in[0];
  const void* wvp = d_in[1];
  const void* emb = d_in[2];
  const void* Wt[2]  = {d_in[3], d_in[9]};
  const void* bt[2]  = {d_in[4], d_in[10]};
  const void* gm[2]  = {d_in[5], d_in[11]};
  const void* bet[2] = {d_in[6], d_in[12]};
  const void* Wo[2]  = {d_in[7], d_in[13]};
  const void* bo[2]  = {d_in[8], d_in[14]};
  const int Kdim[2] = {768, 300};

  // workspace layout (f32 unless noted); XO doubles as X (token GEMM A) then O
  float*  XO     = (float*)d_ws;            // 6291456 f32
  float*  Qb     = XO + 6291456;            // 6291456 f32
  float*  Kb     = Qb + 6291456;            // 6291456 f32
  ushort* Vb     = (ushort*)(Kb + 6291456); // 6291456 bf16
  float*  probsb = (float*)(Vb + 6291456);  // 163840 f32
  float*  colsum = probsb + 163840;         // 8192 f32
  float*  accb   = colsum + 8192;           // 320 f32
  int*    flagp  = (int*)(accb + 320);      // 1 int

  k_detect<<<1, 64, 0, stream>>>((const ushort*)wvp, flagp);

  for (int br=0; br<2; br++){
    if (br==0)
      k_build_x<<<3072, 256, 0, stream>>>(ids, emb, XO, flagp);
    dim3 g1(128, 36);
    k_gemm_qkv<<<g1, 256, 0, stream>>>(br==0 ? XO : nullptr,
                                       br==0 ? nullptr : wvp,
                                       Wt[br], bt[br], Kdim[br], flagp, Qb, Kb, Vb);
    k_norm<<<24576, 256, 0, stream>>>(Qb, Kb, colsum);
    k_attn<<<8192, 256, 0, stream>>>(Qb, Kb, Vb, gm[br], bet[br], flagp, XO, colsum);
    k_probs<<<2048, 256, 0, stream>>>(XO, Wo[br], bo[br], flagp, probsb);
    k_final<<<16, 512, 0, stream>>>(ids, colsum, probsb, flagp, accb, d_out, br);
  }
}

// Round 3
// 1180.980 us; speedup vs baseline: 3.5924x; 3.5924x over previous
//
#include <hip/hip_runtime.h>

typedef unsigned int uint;
typedef unsigned short ushort;
typedef _Float16 f16;
typedef _Float16 h8 __attribute__((ext_vector_type(8)));
typedef float f32x4 __attribute__((ext_vector_type(4)));

// B=16 L=512 H=12 d=64 D=768 N3=2304 C=20 M=8192

__device__ __forceinline__ float b2f(ushort u){ return __uint_as_float(((uint)u)<<16); }
__device__ __forceinline__ ushort f2b(float f){
  uint u = __float_as_uint(f);
  uint r = u + 0x7fffu + ((u>>16)&1u);
  return (ushort)(r>>16);
}
__device__ __forceinline__ float leaky(float x){ return x >= 0.f ? x : 0.01f*x; }
__device__ __forceinline__ float ldf(const void* p, int idx, int isb){
  return isb ? b2f(((const ushort*)p)[idx]) : ((const float*)p)[idx];
}

// ---------- K-1: detect whether float tensors arrived as bf16 (1) or f32 (0) ----------
__global__ void k_detect(const ushort* __restrict__ wvbits, int* __restrict__ flag){
  if (blockIdx.x==0 && threadIdx.x==0){
    int sane = 0;
    for (int i=0;i<128;i++){
      uint e = (wvbits[i]>>7)&0xffu;
      if (e==0u || (e>=90u && e<=150u)) sane++;
    }
    *flag = (sane >= 115) ? 1 : 0;
  }
}

// ---------- K0: X[m,k] = leaky(emb[ids[m],k])  (f32 out) ----------
__global__ __launch_bounds__(256) void k_build_x(const int* __restrict__ ids,
    const void* __restrict__ emb, float* __restrict__ X, const int* __restrict__ flag){
  int isb = *flag;
  int t = blockIdx.x*256 + threadIdx.x;
  int m = t / 96;
  int kk = (t % 96) * 8;
  float o[8];
  if (isb){
    const ushort* src = (const ushort*)emb + (size_t)ids[m]*768 + kk;
    uint4 v = *(const uint4*)src;
    o[0]=__uint_as_float((v.x&0xffffu)<<16); o[1]=__uint_as_float(v.x&0xffff0000u);
    o[2]=__uint_as_float((v.y&0xffffu)<<16); o[3]=__uint_as_float(v.y&0xffff0000u);
    o[4]=__uint_as_float((v.z&0xffffu)<<16); o[5]=__uint_as_float(v.z&0xffff0000u);
    o[6]=__uint_as_float((v.w&0xffffu)<<16); o[7]=__uint_as_float(v.w&0xffff0000u);
  } else {
    const float* src = (const float*)emb + (size_t)ids[m]*768 + kk;
    float4 v0 = ((const float4*)src)[0];
    float4 v1 = ((const float4*)src)[1];
    o[0]=v0.x; o[1]=v0.y; o[2]=v0.z; o[3]=v0.w;
    o[4]=v1.x; o[5]=v1.y; o[6]=v1.z; o[7]=v1.w;
  }
  float* dst = X + (size_t)m*768 + kk;
  #pragma unroll
  for (int i=0;i<8;i++) dst[i] = leaky(o[i]);
}

// ---------- K1: QKV GEMM: y = leaky(A @ W^T + b); Q,K -> fp16 [b,h,l,d]; V -> fp16 transposed [b,h,d,l] ----------
__global__ __launch_bounds__(256) void k_gemm_qkv(const float* __restrict__ Aws,
    const void* __restrict__ Aext, const void* __restrict__ W,
    const void* __restrict__ bias, int K, const int* __restrict__ flag,
    f16* __restrict__ Qh, f16* __restrict__ Kh, f16* __restrict__ Vt){
  __shared__ __align__(16) float As[16][68];
  __shared__ __align__(16) float Bs[16][68];
  int isb = *flag;
  int tid = threadIdx.x;
  int tx = tid & 15, ty = tid >> 4;
  int m0 = blockIdx.x * 64, n0 = blockIdx.y * 64;
  int ml = tid >> 2;
  int kq = (tid & 3) << 2;
  float acc[4][4] = {};
  int steps = (K + 15) >> 4;
  for (int s0 = 0; s0 < steps; s0++){
    int k = s0*16 + kq;
    float a0=0.f,a1=0.f,a2=0.f,a3=0.f, b0=0.f,b1=0.f,b2=0.f,b3=0.f;
    if (k < K){
      if (Aws){
        float4 va = *(const float4*)(Aws + (size_t)(m0+ml)*K + k);
        a0=va.x; a1=va.y; a2=va.z; a3=va.w;
      } else if (isb){
        uint2 va = *(const uint2*)((const ushort*)Aext + (size_t)(m0+ml)*K + k);
        a0=__uint_as_float((va.x&0xffffu)<<16); a1=__uint_as_float(va.x&0xffff0000u);
        a2=__uint_as_float((va.y&0xffffu)<<16); a3=__uint_as_float(va.y&0xffff0000u);
      } else {
        float4 va = *(const float4*)((const float*)Aext + (size_t)(m0+ml)*K + k);
        a0=va.x; a1=va.y; a2=va.z; a3=va.w;
      }
      if (isb){
        uint2 vb = *(const uint2*)((const ushort*)W + (size_t)(n0+ml)*K + k);
        b0=__uint_as_float((vb.x&0xffffu)<<16); b1=__uint_as_float(vb.x&0xffff0000u);
        b2=__uint_as_float((vb.y&0xffffu)<<16); b3=__uint_as_float(vb.y&0xffff0000u);
      } else {
        float4 vb = *(const float4*)((const float*)W + (size_t)(n0+ml)*K + k);
        b0=vb.x; b1=vb.y; b2=vb.z; b3=vb.w;
      }
    }
    As[kq+0][ml]=a0; As[kq+1][ml]=a1; As[kq+2][ml]=a2; As[kq+3][ml]=a3;
    Bs[kq+0][ml]=b0; Bs[kq+1][ml]=b1; Bs[kq+2][ml]=b2; Bs[kq+3][ml]=b3;
    __syncthreads();
    #pragma unroll
    for (int kt=0; kt<16; kt++){
      float4 av = *(const float4*)&As[kt][ty*4];
      float4 bv = *(const float4*)&Bs[kt][tx*4];
      acc[0][0] += av.x*bv.x; acc[0][1] += av.x*bv.y; acc[0][2] += av.x*bv.z; acc[0][3] += av.x*bv.w;
      acc[1][0] += av.y*bv.x; acc[1][1] += av.y*bv.y; acc[1][2] += av.y*bv.z; acc[1][3] += av.y*bv.w;
      acc[2][0] += av.z*bv.x; acc[2][1] += av.z*bv.y; acc[2][2] += av.z*bv.z; acc[2][3] += av.z*bv.w;
      acc[3][0] += av.w*bv.x; acc[3][1] += av.w*bv.y; acc[3][2] += av.w*bv.z; acc[3][3] += av.w*bv.w;
    }
    __syncthreads();
  }
  int s = n0 / 768;
  int h = (n0 % 768) >> 6;
  #pragma unroll
  for (int i=0;i<4;i++){
    int m = m0 + ty*4 + i;
    int bq = m >> 9, l = m & 511;
    size_t rowbase = ((size_t)(bq*12 + h)*512 + l)*64;
    #pragma unroll
    for (int j=0;j<4;j++){
      int dd = tx*4 + j;
      float y = acc[i][j] + ldf(bias, n0 + dd, isb);
      y = leaky(y);
      if (s == 0)      Qh[rowbase + dd] = (f16)y;
      else if (s == 1) Kh[rowbase + dd] = (f16)y;
      else             Vt[((size_t)(bq*12 + h)*64 + dd)*512 + l] = (f16)y;
    }
  }
}

// ---------- K2: row-normalize Q,K (over d=64) in place (fp16); also zero colsum ----------
__global__ __launch_bounds__(256) void k_norm(f16* __restrict__ Qh, f16* __restrict__ Kh,
    float* __restrict__ colsum){
  int tid = threadIdx.x;
  int wv = tid >> 6, lane = tid & 63;
  int row = blockIdx.x*4 + wv;
  size_t base = (size_t)row*64 + lane;
  float q = (float)Qh[base];
  float ssq = q*q;
  #pragma unroll
  for (int off=1; off<64; off<<=1) ssq += __shfl_xor(ssq, off, 64);
  Qh[base] = (f16)(q / fmaxf(sqrtf(ssq), 1e-8f));
  float k = (float)Kh[base];
  float ssk = k*k;
  #pragma unroll
  for (int off=1; off<64; off<<=1) ssk += __shfl_xor(ssk, off, 64);
  Kh[base] = (f16)(k / fmaxf(sqrtf(ssk), 1e-8f));
  if (blockIdx.x < 32) colsum[blockIdx.x*256 + tid] = 0.f;
}

// ---------- K3: fused attention, MFMA, two-sweep (no att materialization) ----------
// block = (b, i-tile of 16). Sweep0: scores->LN->exp->rowsums l. Sweep1: recompute,
// colsum (with known l), P@V via MFMA. O[b,l,768] f32.
__global__ __launch_bounds__(256) void k_attn2(const f16* __restrict__ Qh,
    const f16* __restrict__ Kh, const f16* __restrict__ Vt,
    const void* __restrict__ gamma, const void* __restrict__ beta,
    const int* __restrict__ flag,
    float* __restrict__ O, float* __restrict__ colsum){
  constexpr int ZS = 421;   // f32 stride per i row (32 j * 13 + 5 pad)
  constexpr int TS = 40;    // zt: ushort stride per i row (32 j + 8 pad, 16B-aligned)
  __shared__ float z[16*ZS];          // raw scores, [i][j*13 + h]
  __shared__ f16   zt[12*16*TS];      // e (fp16), [h][i][j]
  __shared__ float rsL[192];          // 1/l  [h*16+i]
  __shared__ float csL[32];
  __shared__ float gL[12], beL[12];

  int tid = threadIdx.x;
  int w = tid >> 6, lane = tid & 63;
  int kq = lane >> 4, mrow = lane & 15;
  int bx = blockIdx.x;
  int b = bx >> 5, i0 = (bx & 31) << 4;
  int pj = tid & 31, pi = tid >> 5;   // stats positions: (pi,pj) and (pi+8,pj)

  if (tid < 12){ int isb = *flag; gL[tid] = ldf(gamma, tid, isb); beL[tid] = ldf(beta, tid, isb); }
  if (tid < 32) csL[tid] = 0.f;

  // K-row A-fragments: 3 heads per wave, 2 K-steps (d=64)
  h8 ak[3][2];
  #pragma unroll
  for (int hh=0; hh<3; hh++){
    int h = w*3 + hh;
    const f16* kb = Kh + ((size_t)(b*12+h)*512 + i0 + mrow)*64;
    #pragma unroll
    for (int ks=0; ks<2; ks++)
      ak[hh][ks] = *(const h8*)(kb + ks*32 + kq*8);
  }
  f32x4 oacc[3][4];
  #pragma unroll
  for (int hh=0; hh<3; hh++)
    #pragma unroll
    for (int nt=0; nt<4; nt++)
      oacc[hh][nt] = (f32x4){0.f,0.f,0.f,0.f};
  float racc[2][12];
  #pragma unroll
  for (int p=0;p<2;p++)
    #pragma unroll
    for (int h=0;h<12;h++) racc[p][h] = 0.f;

  __syncthreads();

  for (int sweep=0; sweep<2; sweep++){
    for (int jt=0; jt<16; jt++){
      // ---- QK^T: S[16 x 32] for this wave's 3 heads ----
      #pragma unroll
      for (int hh=0; hh<3; hh++){
        int h = w*3 + hh;
        const f16* qb = Qh + ((size_t)(b*12+h)*512 + jt*32)*64;
        #pragma unroll
        for (int jn=0; jn<2; jn++){
          f32x4 c = (f32x4){0.f,0.f,0.f,0.f};
          #pragma unroll
          for (int ks=0; ks<2; ks++){
            h8 bf = *(const h8*)(qb + (size_t)(jn*16 + mrow)*64 + ks*32 + kq*8);
            c = __builtin_amdgcn_mfma_f32_16x16x32_f16(ak[hh][ks], bf, c, 0, 0, 0);
          }
          int jl = jn*16 + mrow;
          #pragma unroll
          for (int r=0;r<4;r++)
            z[(kq*4 + r)*ZS + jl*13 + h] = c[r];
        }
      }
      __syncthreads();
      // ---- LN over heads + exp (+ rowsum / colsum) ----
      #pragma unroll
      for (int p=0; p<2; p++){
        int i = pi + p*8, j = pj;
        const float* zp = &z[i*ZS + j*13];
        float s[12];
        float mu = 0.f, sq = 0.f;
        #pragma unroll
        for (int h=0;h<12;h++){ s[h] = zp[h]; mu += s[h]; sq += s[h]*s[h]; }
        mu *= (1.f/12.f);
        float var = fmaxf(sq*(1.f/12.f) - mu*mu, 0.f);
        float rstd = rsqrtf(var + 1e-5f);
        if (sweep == 0){
          #pragma unroll
          for (int h=0;h<12;h++){
            float e = __expf((s[h]-mu)*rstd*gL[h] + beL[h]);
            racc[p][h] += e;
          }
        } else {
          float cacc = 0.f;
          #pragma unroll
          for (int h=0;h<12;h++){
            float e = __expf((s[h]-mu)*rstd*gL[h] + beL[h]);
            zt[(h*16 + i)*TS + j] = (f16)e;
            cacc += e * rsL[h*16 + i];
          }
          atomicAdd(&csL[j], cacc*(1.f/12.f));
        }
      }
      if (sweep == 0){
        __syncthreads();           // protect z before next jt's stores
      } else {
        __syncthreads();           // zt + csL ready; z dead
        // ---- P@V: MFMA from LDS e-tile (A) x global Vt (B) ----
        #pragma unroll
        for (int hh=0; hh<3; hh++){
          int h = w*3 + hh;
          h8 pa = *(const h8*)&zt[(h*16 + mrow)*TS + kq*8];
          const f16* vb = Vt + ((size_t)(b*12+h)*64)*512;
          #pragma unroll
          for (int nt=0; nt<4; nt++){
            h8 bf = *(const h8*)(vb + (size_t)(nt*16 + mrow)*512 + jt*32 + kq*8);
            oacc[hh][nt] = __builtin_amdgcn_mfma_f32_16x16x32_f16(pa, bf, oacc[hh][nt], 0, 0, 0);
          }
        }
        if (tid < 32){
          atomicAdd(&colsum[b*512 + jt*32 + tid], csL[tid]);
          csL[tid] = 0.f;
        }
        // no barrier needed: next-jt writes to z (dead) and zt/csL rewrites are
        // separated from these reads by the next post-store barrier.
      }
    }
    if (sweep == 0){
      // reduce rowsums over the 32 j-lanes sharing each i (wave-local)
      #pragma unroll
      for (int p=0;p<2;p++){
        #pragma unroll
        for (int h=0;h<12;h++){
          float v = racc[p][h];
          #pragma unroll
          for (int m=1; m<32; m<<=1) v += __shfl_xor(v, m);
          if ((lane & 31) == 0) rsL[h*16 + (pi + p*8)] = 1.f / v;
        }
      }
      __syncthreads();
    }
  }
  // ---- epilogue: O[b, i0+i, h*64+d] = oacc / l ----
  #pragma unroll
  for (int hh=0; hh<3; hh++){
    int h = w*3 + hh;
    #pragma unroll
    for (int nt=0; nt<4; nt++){
      #pragma unroll
      for (int r=0;r<4;r++){
        int i = kq*4 + r;
        float val = oacc[hh][nt][r] * rsL[h*16 + i];
        O[((size_t)(b*512) + i0 + i)*768 + h*64 + nt*16 + mrow] = val;
      }
    }
  }
}

// ---------- K4: probs[m,:] = softmax(O[m,:] @ Wout^T + bout) ----------
__global__ __launch_bounds__(256) void k_probs(const float* __restrict__ O,
    const void* __restrict__ Wout, const void* __restrict__ bout,
    const int* __restrict__ flag, float* __restrict__ probs){
  int isb = *flag;
  int tid = threadIdx.x, wv = tid>>6, lane = tid&63;
  int m = blockIdx.x*4 + wv;
  const float* orow = O + (size_t)m*768;
  float acc[20];
  #pragma unroll
  for (int c=0;c<20;c++) acc[c]=0.f;
  for (int kk=0; kk<12; kk++){
    float o = orow[kk*64 + lane];
    #pragma unroll
    for (int c=0;c<20;c++)
      acc[c] += o * ldf(Wout, c*768 + kk*64 + lane, isb);
  }
  #pragma unroll
  for (int c=0;c<20;c++){
    #pragma unroll
    for (int off=1; off<64; off<<=1) acc[c] += __shfl_xor(acc[c], off, 64);
  }
  float mx = -3.4e38f;
  #pragma unroll
  for (int c=0;c<20;c++){ acc[c] += ldf(bout, c, isb); mx = fmaxf(mx, acc[c]); }
  float s=0.f;
  #pragma unroll
  for (int c=0;c<20;c++){ acc[c] = __expf(acc[c]-mx); s += acc[c]; }
  float inv = 1.f/s;
  if (lane == 0){
    float* pr = probs + (size_t)m*20;
    #pragma unroll
    for (int c=0;c<20;c++) pr[c] = acc[c]*inv;
  }
}

// ---------- K5: weights = softmax(mask*colsum); out[b,:] = sum_l w[l]*probs[b,l,:] ----------
__global__ __launch_bounds__(512) void k_final(const int* __restrict__ ids,
    const float* __restrict__ colsum, const float* __restrict__ probs,
    const int* __restrict__ flag,
    float* __restrict__ accb, void* __restrict__ outp, int br){
  __shared__ float red[8];
  __shared__ float bcast;
  __shared__ float pacc[8][20];
  int b = blockIdx.x, tid = threadIdx.x;
  int wv = tid>>6, lane = tid&63;
  float w = (ids[b*512+tid] != 0) ? colsum[b*512+tid] : 0.f;
  float mx = w;
  #pragma unroll
  for (int off=1; off<64; off<<=1) mx = fmaxf(mx, __shfl_xor(mx, off, 64));
  if (lane==0) red[wv] = mx;
  __syncthreads();
  if (tid==0){ float m2 = red[0]; for (int k2=1;k2<8;k2++) m2 = fmaxf(m2, red[k2]); bcast = m2; }
  __syncthreads();
  float M = bcast;
  float e = __expf(w - M);
  float s = e;
  #pragma unroll
  for (int off=1; off<64; off<<=1) s += __shfl_xor(s, off, 64);
  if (lane==0) red[wv] = s;
  __syncthreads();
  if (tid==0){ float s2=0.f; for (int k2=0;k2<8;k2++) s2 += red[k2]; bcast = s2; }
  __syncthreads();
  float wn = e / bcast;
  float p[20];
  const float* pr = probs + ((size_t)b*512 + tid)*20;
  #pragma unroll
  for (int c=0;c<20;c++) p[c] = wn * pr[c];
  #pragma unroll
  for (int c=0;c<20;c++){
    #pragma unroll
    for (int off=1; off<64; off<<=1) p[c] += __shfl_xor(p[c], off, 64);
  }
  if (lane==0){
    #pragma unroll
    for (int c=0;c<20;c++) pacc[wv][c] = p[c];
  }
  __syncthreads();
  if (tid < 20){
    float s2 = 0.f;
    #pragma unroll
    for (int k2=0;k2<8;k2++) s2 += pacc[k2][tid];
    if (br == 0) accb[b*20 + tid] = s2;
    else {
      float v = (accb[b*20 + tid] + s2) * 0.5f;
      if (*flag) ((ushort*)outp)[b*20 + tid] = f2b(v);
      else       ((float*)outp)[b*20 + tid] = v;
    }
  }
}

extern "C" void kernel_launch(void* const* d_in, const int* in_sizes, int n_in,
                              void* d_out, int out_size, void* d_ws, size_t ws_size,
                              hipStream_t stream){
  (void)in_sizes; (void)n_in; (void)out_size; (void)ws_size;
  const int*  ids = (const int*)d_in[0];
  const void* wvp = d_in[1];
  const void* emb = d_in[2];
  const void* Wt[2]  = {d_in[3], d_in[9]};
  const void* bt[2]  = {d_in[4], d_in[10]};
  const void* gm[2]  = {d_in[5], d_in[11]};
  const void* bet[2] = {d_in[6], d_in[12]};
  const void* Wo[2]  = {d_in[7], d_in[13]};
  const void* bo[2]  = {d_in[8], d_in[14]};
  const int Kdim[2] = {768, 300};

  // ws layout: XO (X then O) f32; Qh/Kh fp16 [b,h,l,d]; Vt fp16 [b,h,d,l]
  float*  XO     = (float*)d_ws;            // 6291456 f32
  f16*    Qh     = (f16*)(XO + 6291456);    // 6291456 f16
  f16*    Kh     = Qh + 6291456;            // 6291456 f16
  f16*    Vt     = Kh + 6291456;            // 6291456 f16
  float*  probsb = (float*)(Vt + 6291456);  // 163840 f32
  float*  colsum = probsb + 163840;         // 8192 f32
  float*  accb   = colsum + 8192;           // 320 f32
  int*    flagp  = (int*)(accb + 320);      // 1 int

  k_detect<<<1, 64, 0, stream>>>((const ushort*)wvp, flagp);

  for (int br=0; br<2; br++){
    if (br==0)
      k_build_x<<<3072, 256, 0, stream>>>(ids, emb, XO, flagp);
    dim3 g1(128, 36);
    k_gemm_qkv<<<g1, 256, 0, stream>>>(br==0 ? XO : nullptr,
                                       br==0 ? nullptr : wvp,
                                       Wt[br], bt[br], Kdim[br], flagp, Qh, Kh, Vt);
    k_norm<<<24576, 256, 0, stream>>>(Qh, Kh, colsum);
    k_attn2<<<512, 256, 0, stream>>>(Qh, Kh, Vt, gm[br], bet[br], flagp, XO, colsum);
    k_probs<<<2048, 256, 0, stream>>>(XO, Wo[br], bo[br], flagp, probsb);
    k_final<<<16, 512, 0, stream>>>(ids, colsum, probsb, flagp, accb, d_out, br);
  }
}

// Round 4
// 803.706 us; speedup vs baseline: 5.2787x; 1.4694x over previous
//
#include <hip/hip_runtime.h>

typedef unsigned int uint;
typedef unsigned short ushort;
typedef _Float16 f16;
typedef _Float16 h8 __attribute__((ext_vector_type(8)));
typedef float f32x4 __attribute__((ext_vector_type(4)));

// B=16 L=512 H=12 d=64 D=768 N3=2304 C=20 M=8192

__device__ __forceinline__ float b2f(ushort u){ return __uint_as_float(((uint)u)<<16); }
__device__ __forceinline__ ushort f2b(float f){
  uint u = __float_as_uint(f);
  uint r = u + 0x7fffu + ((u>>16)&1u);
  return (ushort)(r>>16);
}
__device__ __forceinline__ float leaky(float x){ return x >= 0.f ? x : 0.01f*x; }
__device__ __forceinline__ float ldf(const void* p, int idx, int isb){
  return isb ? b2f(((const ushort*)p)[idx]) : ((const float*)p)[idx];
}

// ---------- K-1: detect whether float tensors arrived as bf16 (1) or f32 (0) ----------
__global__ void k_detect(const ushort* __restrict__ wvbits, int* __restrict__ flag){
  if (blockIdx.x==0 && threadIdx.x==0){
    int sane = 0;
    for (int i=0;i<128;i++){
      uint e = (wvbits[i]>>7)&0xffu;
      if (e==0u || (e>=90u && e<=150u)) sane++;
    }
    *flag = (sane >= 115) ? 1 : 0;
  }
}

// ---------- K0: Ah[m,k] = leaky(emb[ids[m],k])  (fp16 out, KP=768) ----------
__global__ __launch_bounds__(256) void k_build_x(const int* __restrict__ ids,
    const void* __restrict__ emb, f16* __restrict__ Ah, const int* __restrict__ flag){
  int isb = *flag;
  int t = blockIdx.x*256 + threadIdx.x;
  int m = t / 96;
  int kk = (t % 96) * 8;
  float o[8];
  if (isb){
    const ushort* src = (const ushort*)emb + (size_t)ids[m]*768 + kk;
    uint4 v = *(const uint4*)src;
    o[0]=__uint_as_float((v.x&0xffffu)<<16); o[1]=__uint_as_float(v.x&0xffff0000u);
    o[2]=__uint_as_float((v.y&0xffffu)<<16); o[3]=__uint_as_float(v.y&0xffff0000u);
    o[4]=__uint_as_float((v.z&0xffffu)<<16); o[5]=__uint_as_float(v.z&0xffff0000u);
    o[6]=__uint_as_float((v.w&0xffffu)<<16); o[7]=__uint_as_float(v.w&0xffff0000u);
  } else {
    const float* src = (const float*)emb + (size_t)ids[m]*768 + kk;
    float4 v0 = ((const float4*)src)[0];
    float4 v1 = ((const float4*)src)[1];
    o[0]=v0.x; o[1]=v0.y; o[2]=v0.z; o[3]=v0.w;
    o[4]=v1.x; o[5]=v1.y; o[6]=v1.z; o[7]=v1.w;
  }
  h8 hv;
  #pragma unroll
  for (int i=0;i<8;i++) hv[i] = (f16)leaky(o[i]);
  *(h8*)(Ah + (size_t)m*768 + kk) = hv;
}

// ---------- K0b: generic fp16 repack with zero-pad: dst[n,KP] from src[n,Ksrc] ----------
__global__ __launch_bounds__(256) void k_prep(const void* __restrict__ src,
    f16* __restrict__ dst, int Ksrc, int kp8, const int* __restrict__ flag){
  int isb = *flag;
  int t = blockIdx.x*256 + threadIdx.x;
  int n = t / kp8;
  int kk = (t % kp8) * 8;
  h8 hv;
  #pragma unroll
  for (int i=0;i<8;i++){
    int k = kk + i;
    hv[i] = (k < Ksrc) ? (f16)ldf(src, n*Ksrc + k, isb) : (f16)0.f;
  }
  *(h8*)(dst + (size_t)n*(kp8*8) + kk) = hv;
}

// ---------- K1: MFMA QKV GEMM: y = leaky(A @ W^T + b); Q,K fp16 [b,h,l,d]; V fp16 [b,h,d,l] ----------
// LDS-free: per wave 64x64 output (4x4 frags of 16x16x32), A/B frags direct from global,
// double-buffered in registers. Block = 4 waves = 64 M x 256 N.
template<int KP>
__global__ __launch_bounds__(256) void k_gemm_mfma(const f16* __restrict__ Ah,
    const f16* __restrict__ Wh, const void* __restrict__ bias, const int* __restrict__ flag,
    f16* __restrict__ Qh, f16* __restrict__ Kh, f16* __restrict__ Vt){
  constexpr int STEPS = KP/32;
  int tid = threadIdx.x;
  int w = tid >> 6, lane = tid & 63;
  int mrow = lane & 15, kq = lane >> 4;
  int m0 = blockIdx.x * 64;
  int n0 = blockIdx.y * 256 + w * 64;

  const f16* ap = Ah + (size_t)(m0 + mrow)*KP + kq*8;
  const f16* bp = Wh + (size_t)(n0 + mrow)*KP + kq*8;

  f32x4 acc[4][4];
  #pragma unroll
  for (int mt=0; mt<4; mt++)
    #pragma unroll
    for (int nt=0; nt<4; nt++) acc[mt][nt] = (f32x4){0.f,0.f,0.f,0.f};

  h8 a0[4], b0[4], a1[4], b1[4];
#define LOADA(buf, step) { const f16* p_ = ap + (step)*32; \
  buf[0]=*(const h8*)(p_); buf[1]=*(const h8*)(p_+(size_t)16*KP); \
  buf[2]=*(const h8*)(p_+(size_t)32*KP); buf[3]=*(const h8*)(p_+(size_t)48*KP); }
#define LOADB(buf, step) { const f16* p_ = bp + (step)*32; \
  buf[0]=*(const h8*)(p_); buf[1]=*(const h8*)(p_+(size_t)16*KP); \
  buf[2]=*(const h8*)(p_+(size_t)32*KP); buf[3]=*(const h8*)(p_+(size_t)48*KP); }
#define MM(A_, B_) { \
  _Pragma("unroll") for (int mt=0; mt<4; mt++) \
    _Pragma("unroll") for (int nt=0; nt<4; nt++) \
      acc[mt][nt] = __builtin_amdgcn_mfma_f32_16x16x32_f16(A_[mt], B_[nt], acc[mt][nt], 0, 0, 0); }

  LOADA(a0, 0); LOADB(b0, 0);
  #pragma unroll
  for (int ks=0; ks<STEPS; ks+=2){
    LOADA(a1, ks+1); LOADB(b1, ks+1);
    MM(a0, b0);
    if (ks+2 < STEPS){ LOADA(a0, ks+2); LOADB(b0, ks+2); }
    MM(a1, b1);
  }
#undef LOADA
#undef LOADB
#undef MM

  int isb = *flag;
  int s = n0 / 768;
  int h = (n0 % 768) >> 6;
  float bv[4];
  #pragma unroll
  for (int nt=0; nt<4; nt++) bv[nt] = ldf(bias, n0 + nt*16 + mrow, isb);

  #pragma unroll
  for (int mt=0; mt<4; mt++){
    #pragma unroll
    for (int nt=0; nt<4; nt++){
      #pragma unroll
      for (int r=0; r<4; r++){
        int m = m0 + mt*16 + kq*4 + r;      // D row = (lane>>4)*4+reg
        int dd = nt*16 + mrow;               // D col = lane&15
        float y = leaky(acc[mt][nt][r] + bv[nt]);
        int bq = m >> 9, l = m & 511;
        if (s == 0)      Qh[((size_t)(bq*12 + h)*512 + l)*64 + dd] = (f16)y;
        else if (s == 1) Kh[((size_t)(bq*12 + h)*512 + l)*64 + dd] = (f16)y;
        else             Vt[((size_t)(bq*12 + h)*64 + dd)*512 + l] = (f16)y;
      }
    }
  }
}

// ---------- K2: row-normalize Q,K (over d=64) in place (fp16); also zero colsum ----------
__global__ __launch_bounds__(256) void k_norm(f16* __restrict__ Qh, f16* __restrict__ Kh,
    float* __restrict__ colsum){
  int tid = threadIdx.x;
  int wv = tid >> 6, lane = tid & 63;
  int row = blockIdx.x*4 + wv;
  size_t base = (size_t)row*64 + lane;
  float q = (float)Qh[base];
  float ssq = q*q;
  #pragma unroll
  for (int off=1; off<64; off<<=1) ssq += __shfl_xor(ssq, off, 64);
  Qh[base] = (f16)(q / fmaxf(sqrtf(ssq), 1e-8f));
  float k = (float)Kh[base];
  float ssk = k*k;
  #pragma unroll
  for (int off=1; off<64; off<<=1) ssk += __shfl_xor(ssk, off, 64);
  Kh[base] = (f16)(k / fmaxf(sqrtf(ssk), 1e-8f));
  if (blockIdx.x < 32) colsum[blockIdx.x*256 + tid] = 0.f;
}

// ---------- K3: fused attention, MFMA, two-sweep (no att materialization) ----------
__global__ __launch_bounds__(256) void k_attn2(const f16* __restrict__ Qh,
    const f16* __restrict__ Kh, const f16* __restrict__ Vt,
    const void* __restrict__ gamma, const void* __restrict__ beta,
    const int* __restrict__ flag,
    float* __restrict__ O, float* __restrict__ colsum){
  constexpr int ZS = 421;
  constexpr int TS = 40;
  __shared__ float z[16*ZS];
  __shared__ f16   zt[12*16*TS];
  __shared__ float rsL[192];
  __shared__ float csL[32];
  __shared__ float gL[12], beL[12];

  int tid = threadIdx.x;
  int w = tid >> 6, lane = tid & 63;
  int kq = lane >> 4, mrow = lane & 15;
  int bx = blockIdx.x;
  int b = bx >> 5, i0 = (bx & 31) << 4;
  int pj = tid & 31, pi = tid >> 5;

  if (tid < 12){ int isb = *flag; gL[tid] = ldf(gamma, tid, isb); beL[tid] = ldf(beta, tid, isb); }
  if (tid < 32) csL[tid] = 0.f;

  h8 ak[3][2];
  #pragma unroll
  for (int hh=0; hh<3; hh++){
    int h = w*3 + hh;
    const f16* kb = Kh + ((size_t)(b*12+h)*512 + i0 + mrow)*64;
    #pragma unroll
    for (int ks=0; ks<2; ks++)
      ak[hh][ks] = *(const h8*)(kb + ks*32 + kq*8);
  }
  f32x4 oacc[3][4];
  #pragma unroll
  for (int hh=0; hh<3; hh++)
    #pragma unroll
    for (int nt=0; nt<4; nt++)
      oacc[hh][nt] = (f32x4){0.f,0.f,0.f,0.f};
  float racc[2][12];
  #pragma unroll
  for (int p=0;p<2;p++)
    #pragma unroll
    for (int h=0;h<12;h++) racc[p][h] = 0.f;

  __syncthreads();

  for (int sweep=0; sweep<2; sweep++){
    for (int jt=0; jt<16; jt++){
      #pragma unroll
      for (int hh=0; hh<3; hh++){
        int h = w*3 + hh;
        const f16* qb = Qh + ((size_t)(b*12+h)*512 + jt*32)*64;
        #pragma unroll
        for (int jn=0; jn<2; jn++){
          f32x4 c = (f32x4){0.f,0.f,0.f,0.f};
          #pragma unroll
          for (int ks=0; ks<2; ks++){
            h8 bf = *(const h8*)(qb + (size_t)(jn*16 + mrow)*64 + ks*32 + kq*8);
            c = __builtin_amdgcn_mfma_f32_16x16x32_f16(ak[hh][ks], bf, c, 0, 0, 0);
          }
          int jl = jn*16 + mrow;
          #pragma unroll
          for (int r=0;r<4;r++)
            z[(kq*4 + r)*ZS + jl*13 + h] = c[r];
        }
      }
      __syncthreads();
      #pragma unroll
      for (int p=0; p<2; p++){
        int i = pi + p*8, j = pj;
        const float* zp = &z[i*ZS + j*13];
        float s[12];
        float mu = 0.f, sq = 0.f;
        #pragma unroll
        for (int h=0;h<12;h++){ s[h] = zp[h]; mu += s[h]; sq += s[h]*s[h]; }
        mu *= (1.f/12.f);
        float var = fmaxf(sq*(1.f/12.f) - mu*mu, 0.f);
        float rstd = rsqrtf(var + 1e-5f);
        if (sweep == 0){
          #pragma unroll
          for (int h=0;h<12;h++){
            float e = __expf((s[h]-mu)*rstd*gL[h] + beL[h]);
            racc[p][h] += e;
          }
        } else {
          float cacc = 0.f;
          #pragma unroll
          for (int h=0;h<12;h++){
            float e = __expf((s[h]-mu)*rstd*gL[h] + beL[h]);
            zt[(h*16 + i)*TS + j] = (f16)e;
            cacc += e * rsL[h*16 + i];
          }
          atomicAdd(&csL[j], cacc*(1.f/12.f));
        }
      }
      if (sweep == 0){
        __syncthreads();
      } else {
        __syncthreads();
        #pragma unroll
        for (int hh=0; hh<3; hh++){
          int h = w*3 + hh;
          h8 pa = *(const h8*)&zt[(h*16 + mrow)*TS + kq*8];
          const f16* vb = Vt + ((size_t)(b*12+h)*64)*512;
          #pragma unroll
          for (int nt=0; nt<4; nt++){
            h8 bf = *(const h8*)(vb + (size_t)(nt*16 + mrow)*512 + jt*32 + kq*8);
            oacc[hh][nt] = __builtin_amdgcn_mfma_f32_16x16x32_f16(pa, bf, oacc[hh][nt], 0, 0, 0);
          }
        }
        if (tid < 32){
          atomicAdd(&colsum[b*512 + jt*32 + tid], csL[tid]);
          csL[tid] = 0.f;
        }
      }
    }
    if (sweep == 0){
      #pragma unroll
      for (int p=0;p<2;p++){
        #pragma unroll
        for (int h=0;h<12;h++){
          float v = racc[p][h];
          #pragma unroll
          for (int m=1; m<32; m<<=1) v += __shfl_xor(v, m);
          if ((lane & 31) == 0) rsL[h*16 + (pi + p*8)] = 1.f / v;
        }
      }
      __syncthreads();
    }
  }
  #pragma unroll
  for (int hh=0; hh<3; hh++){
    int h = w*3 + hh;
    #pragma unroll
    for (int nt=0; nt<4; nt++){
      #pragma unroll
      for (int r=0;r<4;r++){
        int i = kq*4 + r;
        float val = oacc[hh][nt][r] * rsL[h*16 + i];
        O[((size_t)(b*512) + i0 + i)*768 + h*64 + nt*16 + mrow] = val;
      }
    }
  }
}

// ---------- K4: probs[m,:] = softmax(O[m,:] @ Wout^T + bout) ----------
__global__ __launch_bounds__(256) void k_probs(const float* __restrict__ O,
    const void* __restrict__ Wout, const void* __restrict__ bout,
    const int* __restrict__ flag, float* __restrict__ probs){
  int isb = *flag;
  int tid = threadIdx.x, wv = tid>>6, lane = tid&63;
  int m = blockIdx.x*4 + wv;
  const float* orow = O + (size_t)m*768;
  float acc[20];
  #pragma unroll
  for (int c=0;c<20;c++) acc[c]=0.f;
  for (int kk=0; kk<12; kk++){
    float o = orow[kk*64 + lane];
    #pragma unroll
    for (int c=0;c<20;c++)
      acc[c] += o * ldf(Wout, c*768 + kk*64 + lane, isb);
  }
  #pragma unroll
  for (int c=0;c<20;c++){
    #pragma unroll
    for (int off=1; off<64; off<<=1) acc[c] += __shfl_xor(acc[c], off, 64);
  }
  float mx = -3.4e38f;
  #pragma unroll
  for (int c=0;c<20;c++){ acc[c] += ldf(bout, c, isb); mx = fmaxf(mx, acc[c]); }
  float s=0.f;
  #pragma unroll
  for (int c=0;c<20;c++){ acc[c] = __expf(acc[c]-mx); s += acc[c]; }
  float inv = 1.f/s;
  if (lane == 0){
    float* pr = probs + (size_t)m*20;
    #pragma unroll
    for (int c=0;c<20;c++) pr[c] = acc[c]*inv;
  }
}

// ---------- K5: weights = softmax(mask*colsum); out[b,:] = sum_l w[l]*probs[b,l,:] ----------
__global__ __launch_bounds__(512) void k_final(const int* __restrict__ ids,
    const float* __restrict__ colsum, const float* __restrict__ probs,
    const int* __restrict__ flag,
    float* __restrict__ accb, void* __restrict__ outp, int br){
  __shared__ float red[8];
  __shared__ float bcast;
  __shared__ float pacc[8][20];
  int b = blockIdx.x, tid = threadIdx.x;
  int wv = tid>>6, lane = tid&63;
  float w = (ids[b*512+tid] != 0) ? colsum[b*512+tid] : 0.f;
  float mx = w;
  #pragma unroll
  for (int off=1; off<64; off<<=1) mx = fmaxf(mx, __shfl_xor(mx, off, 64));
  if (lane==0) red[wv] = mx;
  __syncthreads();
  if (tid==0){ float m2 = red[0]; for (int k2=1;k2<8;k2++) m2 = fmaxf(m2, red[k2]); bcast = m2; }
  __syncthreads();
  float M = bcast;
  float e = __expf(w - M);
  float s = e;
  #pragma unroll
  for (int off=1; off<64; off<<=1) s += __shfl_xor(s, off, 64);
  if (lane==0) red[wv] = s;
  __syncthreads();
  if (tid==0){ float s2=0.f; for (int k2=0;k2<8;k2++) s2 += red[k2]; bcast = s2; }
  __syncthreads();
  float wn = e / bcast;
  float p[20];
  const float* pr = probs + ((size_t)b*512 + tid)*20;
  #pragma unroll
  for (int c=0;c<20;c++) p[c] = wn * pr[c];
  #pragma unroll
  for (int c=0;c<20;c++){
    #pragma unroll
    for (int off=1; off<64; off<<=1) p[c] += __shfl_xor(p[c], off, 64);
  }
  if (lane==0){
    #pragma unroll
    for (int c=0;c<20;c++) pacc[wv][c] = p[c];
  }
  __syncthreads();
  if (tid < 20){
    float s2 = 0.f;
    #pragma unroll
    for (int k2=0;k2<8;k2++) s2 += pacc[k2][tid];
    if (br == 0) accb[b*20 + tid] = s2;
    else {
      float v = (accb[b*20 + tid] + s2) * 0.5f;
      if (*flag) ((ushort*)outp)[b*20 + tid] = f2b(v);
      else       ((float*)outp)[b*20 + tid] = v;
    }
  }
}

extern "C" void kernel_launch(void* const* d_in, const int* in_sizes, int n_in,
                              void* d_out, int out_size, void* d_ws, size_t ws_size,
                              hipStream_t stream){
  (void)in_sizes; (void)n_in; (void)out_size; (void)ws_size;
  const int*  ids = (const int*)d_in[0];
  const void* wvp = d_in[1];
  const void* emb = d_in[2];
  const void* Wt[2]  = {d_in[3], d_in[9]};
  const void* bt[2]  = {d_in[4], d_in[10]};
  const void* gm[2]  = {d_in[5], d_in[11]};
  const void* bet[2] = {d_in[6], d_in[12]};
  const void* Wo[2]  = {d_in[7], d_in[13]};
  const void* bo[2]  = {d_in[8], d_in[14]};

  // ws layout: O f32; Qh/Kh fp16 [b,h,l,d]; Vt fp16 [b,h,d,l]; Ah fp16 A-matrix; Wh fp16 weights
  float*  O      = (float*)d_ws;            // 6291456 f32
  f16*    Qh     = (f16*)(O + 6291456);     // 6291456 f16
  f16*    Kh     = Qh + 6291456;            // 6291456 f16
  f16*    Vt     = Kh + 6291456;            // 6291456 f16
  f16*    Ah     = Vt + 6291456;            // 6291456 f16 (8192x768 or 8192x320)
  f16*    Wh     = Ah + 6291456;            // 1769472 f16 (2304x768 or 2304x320)
  float*  probsb = (float*)(Wh + 1769472);  // 163840 f32
  float*  colsum = probsb + 163840;         // 8192 f32
  float*  accb   = colsum + 8192;           // 320 f32
  int*    flagp  = (int*)(accb + 320);      // 1 int

  k_detect<<<1, 64, 0, stream>>>((const ushort*)wvp, flagp);

  for (int br=0; br<2; br++){
    if (br==0){
      k_build_x<<<3072, 256, 0, stream>>>(ids, emb, Ah, flagp);           // A: 8192x768 fp16
      k_prep<<<864, 256, 0, stream>>>(Wt[0], Wh, 768, 96, flagp);          // W: 2304x768 fp16
      dim3 g1(128, 9);
      k_gemm_mfma<768><<<g1, 256, 0, stream>>>(Ah, Wh, bt[0], flagp, Qh, Kh, Vt);
    } else {
      k_prep<<<1280, 256, 0, stream>>>(wvp, Ah, 300, 40, flagp);           // A: 8192x320 fp16 (pad)
      k_prep<<<360, 256, 0, stream>>>(Wt[1], Wh, 300, 40, flagp);          // W: 2304x320 fp16 (pad)
      dim3 g1(128, 9);
      k_gemm_mfma<320><<<g1, 256, 0, stream>>>(Ah, Wh, bt[1], flagp, Qh, Kh, Vt);
    }
    k_norm<<<24576, 256, 0, stream>>>(Qh, Kh, colsum);
    k_attn2<<<512, 256, 0, stream>>>(Qh, Kh, Vt, gm[br], bet[br], flagp, O, colsum);
    k_probs<<<2048, 256, 0, stream>>>(O, Wo[br], bo[br], flagp, probsb);
    k_final<<<16, 512, 0, stream>>>(ids, colsum, probsb, flagp, accb, d_out, br);
  }
}